// Round 9
// baseline (410.727 us; speedup 1.0000x reference)
//
#include <hip/hip_runtime.h>

#define HIDDEN 64
#define INFEAT 128
#define SCALE_C 0.70710678118654752f
#define BN_EPS 1e-5f
#define AGG_GRID 2048
#define RED_BLK 32

// ---------- lane broadcast helpers (VALU readlane, uniform lane index) ----------
__device__ __forceinline__ int rli(int v, int l){ return __builtin_amdgcn_readlane(v, l); }
__device__ __forceinline__ float rlf(float v, int l){
  return __uint_as_float(__builtin_amdgcn_readlane(__float_as_uint(v), l));
}

// ---------- device bodies ----------
__device__ __forceinline__ void hist_body(int bid, const int* __restrict__ src,
    const int* __restrict__ dst, int* __restrict__ degO, int* __restrict__ degI, int E){
  int e = bid * 256 + threadIdx.x;
  if (e < E){
    atomicAdd(&degO[src[e]], 1);
    atomicAdd(&degI[dst[e]], 1);
  }
}

__device__ __forceinline__ void place_body(int bid, const int* __restrict__ src,
    const int* __restrict__ dst, int* __restrict__ cur, int* __restrict__ cs, int E){
  int e = bid * 256 + threadIdx.x;
  if (e < E){
    int pos = atomicAdd(&cur[dst[e]], 1);
    cs[pos] = src[e];
  }
}

// GEMM body: Y[N][64] = X[N][KDIM] @ W[KDIM][64] (+B) (opt: row scale by nrm)
template<int KDIM, bool ADDB, bool SCALEROW>
__device__ __forceinline__ void gemm_body(int bid, const float* __restrict__ X,
    const float* __restrict__ W, const float* __restrict__ B,
    float* __restrict__ Y, const float* __restrict__ nrm, int N)
{
  __shared__ float xl[128 * 33];
  const int tid  = threadIdx.x;
  const int lane = tid & 63;
  const int wid  = __builtin_amdgcn_readfirstlane(tid >> 6);  // wave-uniform
  const int nodehalf = wid >> 1;               // 0/1
  const int c0 = (wid & 1) * 32;               // column offset (uniform)
  const int base = bid * 128;
  const int myNode = nodehalf * 64 + lane;     // 0..127
  const int gnode = base + myNode;

  float acc[32];
  #pragma unroll
  for (int c = 0; c < 32; ++c) acc[c] = ADDB ? B[c0 + c] : 0.f;

  constexpr int NCHUNK = KDIM / 32;
  #pragma unroll 1
  for (int ck = 0; ck < NCHUNK; ++ck){
    __syncthreads();
    #pragma unroll
    for (int i = 0; i < 4; ++i){
      int f  = i * 256 + tid;        // float4 id, 0..1023
      int nd = f >> 3;               // 0..127
      int kq = f & 7;                // 0..7
      float4 v = make_float4(0.f, 0.f, 0.f, 0.f);
      if (base + nd < N)
        v = *(const float4*)(X + (size_t)(base + nd) * KDIM + ck * 32 + kq * 4);
      float* p = &xl[nd * 33 + kq * 4];
      p[0] = v.x; p[1] = v.y; p[2] = v.z; p[3] = v.w;
    }
    __syncthreads();
    const float* wrow = W + (size_t)ck * 32 * HIDDEN + c0;   // uniform base
    #pragma unroll
    for (int k = 0; k < 32; ++k){
      float xv = xl[myNode * 33 + k];
      #pragma unroll
      for (int c = 0; c < 32; ++c)
        acc[c] = fmaf(xv, wrow[k * HIDDEN + c], acc[c]);     // W via s_load
    }
  }

  if (gnode < N){
    float sc = SCALEROW ? nrm[gnode] : 1.f;
    float4* yp = (float4*)(Y + (size_t)gnode * HIDDEN + c0);
    #pragma unroll
    for (int j = 0; j < 8; ++j)
      yp[j] = make_float4(acc[4*j]*sc, acc[4*j+1]*sc, acc[4*j+2]*sc, acc[4*j+3]*sc);
  }
}

// Bresenham role spread
__device__ __forceinline__ int role_gemm_idx(int b, int GB, int TOT, int& histIdx){
  int fb  = (int)(((long)b * GB) / TOT);
  int fb1 = (int)(((long)(b + 1) * GB) / TOT);
  histIdx = b - fb;
  return (fb1 > fb) ? fb : -1;
}

// ---------- mega1: degree histograms || fc GEMM ----------
__global__ __launch_bounds__(256) void k_mega1(const int* __restrict__ src,
    const int* __restrict__ dst, int* __restrict__ degO, int* __restrict__ degI, int E,
    const float* __restrict__ x, const float* __restrict__ fc_w,
    const float* __restrict__ fc_b, float* __restrict__ h, int N, int GB, int TOT){
  int hIdx;
  int g = role_gemm_idx(blockIdx.x, GB, TOT, hIdx);
  if (g >= 0) gemm_body<INFEAT, true, false>(g, x, fc_w, fc_b, h, nullptr, N);
  else        hist_body(hIdx, src, dst, degO, degI, E);
}

// ---------- mega2: CSR placement || gemm1 (t1 = (h@w1)*norm_out) ----------
__global__ __launch_bounds__(256) void k_mega2(const int* __restrict__ src,
    const int* __restrict__ dst, int* __restrict__ cur, int* __restrict__ cs, int E,
    const float* __restrict__ h, const float* __restrict__ w1,
    float* __restrict__ t, const float* __restrict__ norm_out, int N, int GB, int TOT){
  int hIdx;
  int g = role_gemm_idx(blockIdx.x, GB, TOT, hIdx);
  if (g >= 0) gemm_body<HIDDEN, false, true>(g, h, w1, nullptr, t, norm_out, N);
  else        place_body(hIdx, src, dst, cur, cs, E);
}

// ---------- scan step 1 ----------
__global__ void k_scan1(const int* __restrict__ deg, int* __restrict__ bsum, int N){
  __shared__ int sh[256];
  int t = threadIdx.x;
  int i = blockIdx.x * 256 + t;
  sh[t] = (i < N) ? deg[i] : 0;
  __syncthreads();
  for (int ofs = 128; ofs > 0; ofs >>= 1){
    if (t < ofs) sh[t] += sh[t + ofs];
    __syncthreads();
  }
  if (t == 0) bsum[blockIdx.x] = sh[0];
}

// ---------- scan step 2 ----------
__global__ void k_scan2(int* __restrict__ bsum, int NB){
  __shared__ int sh[512];
  int t = threadIdx.x;
  int v = (t < NB) ? bsum[t] : 0;
  sh[t] = v;
  __syncthreads();
  for (int ofs = 1; ofs < 512; ofs <<= 1){
    int u = (t >= ofs) ? sh[t - ofs] : 0;
    __syncthreads();
    sh[t] += u;
    __syncthreads();
  }
  if (t < NB) bsum[t] = sh[t] - v;   // exclusive
}

// ---------- scan step 3: rp, cur, norms ----------
__global__ void k_scan3(const int* __restrict__ degI, const int* __restrict__ degO,
                        const int* __restrict__ bofs, int* __restrict__ rp,
                        int* __restrict__ cur, float* __restrict__ norm_out,
                        float* __restrict__ norm_in, int N, int E){
  __shared__ int sh[256];
  int t = threadIdx.x;
  int i = blockIdx.x * 256 + t;
  int v = (i < N) ? degI[i] : 0;
  sh[t] = v;
  __syncthreads();
  for (int ofs = 1; ofs < 256; ofs <<= 1){
    int u = (t >= ofs) ? sh[t - ofs] : 0;
    __syncthreads();
    sh[t] += u;
    __syncthreads();
  }
  if (i < N){
    int excl = sh[t] - v + bofs[blockIdx.x];
    rp[i] = excl; cur[i] = excl;
    if (i == N - 1) rp[N] = E;
    norm_out[i] = rsqrtf((float)max(degO[i], 1));
    norm_in[i]  = rsqrtf((float)max(v, 1));
  }
}

// ---------- gather accumulate (8-deep pipeline, readlane broadcast) ----------
__device__ __forceinline__ float gather_row(const int* __restrict__ rp,
    const int* __restrict__ cs, const float* __restrict__ t, int n, int lane){
  const int start = rp[n], end = rp[n + 1];
  float acc = 0.f;
  for (int j0 = start; j0 < end; j0 += 64){
    int cnt = end - j0; if (cnt > 64) cnt = 64;
    int sidx = (j0 + lane < end) ? cs[j0 + lane] : 0;
    int d = 0;
    for (; d + 8 <= cnt; d += 8){
      int a0 = rli(sidx, d),   a1 = rli(sidx, d+1);
      int a2 = rli(sidx, d+2), a3 = rli(sidx, d+3);
      int a4 = rli(sidx, d+4), a5 = rli(sidx, d+5);
      int a6 = rli(sidx, d+6), a7 = rli(sidx, d+7);
      float v0 = t[(size_t)a0 * HIDDEN + lane];
      float v1 = t[(size_t)a1 * HIDDEN + lane];
      float v2 = t[(size_t)a2 * HIDDEN + lane];
      float v3 = t[(size_t)a3 * HIDDEN + lane];
      float v4 = t[(size_t)a4 * HIDDEN + lane];
      float v5 = t[(size_t)a5 * HIDDEN + lane];
      float v6 = t[(size_t)a6 * HIDDEN + lane];
      float v7 = t[(size_t)a7 * HIDDEN + lane];
      acc += v0; acc += v1; acc += v2; acc += v3;
      acc += v4; acc += v5; acc += v6; acc += v7;
    }
    for (; d < cnt; ++d)
      acc += t[(size_t)rli(sidx, d) * HIDDEN + lane];
  }
  return acc;
}

// ---------- fused conv1-aggregate + conv2-GEMM (matvec via readlane, w2 in VGPRs) ----------
// One wave per dst node. lane = column. t1 rows pre-scaled by norm_out.
// h = (h + gather(t1)*norm_in + b1)*SC ; t2 = (h_row @ w2) * norm_out
__global__ __launch_bounds__(256) void k_aggmv(const int* __restrict__ rp,
    const int* __restrict__ cs, const float* __restrict__ t1,
    const float* __restrict__ norm_in, const float* __restrict__ norm_out,
    const float* __restrict__ b, const float* __restrict__ w2,
    float* __restrict__ h, float* __restrict__ t2, int N)
{
  const int tid = threadIdx.x;
  const int lane = tid & 63;
  const int wv = (blockIdx.x * 256 + tid) >> 6;
  const int nw = (gridDim.x * 256) >> 6;
  const float bv = b[lane];

  float w2r[64];                               // column `lane` of w2
  #pragma unroll
  for (int k = 0; k < 64; ++k) w2r[k] = w2[k * HIDDEN + lane];

  for (int n = wv; n < N; n += nw){
    float acc = gather_row(rp, cs, t1, n, lane);
    size_t idx = (size_t)n * HIDDEN + lane;
    float v = (h[idx] + acc * norm_in[n] + bv) * SCALE_C;
    h[idx] = v;
    // matvec: t2[n][lane] = norm_out[n] * sum_k v_k * w2[k][lane]
    float ta = 0.f, tb = 0.f;
    #pragma unroll
    for (int k = 0; k < 64; k += 2){
      ta = fmaf(rlf(v, k),     w2r[k],     ta);
      tb = fmaf(rlf(v, k + 1), w2r[k + 1], tb);
    }
    t2[idx] = (ta + tb) * norm_out[n];
  }
}

// ---------- conv2 aggregate + BN partials ----------
__global__ __launch_bounds__(256) void k_agg2(const int* __restrict__ rp,
    const int* __restrict__ cs, const float* __restrict__ t2,
    const float* __restrict__ norm_in, const float* __restrict__ b,
    float* __restrict__ h, float* __restrict__ bnpart, int N)
{
  const int tid = threadIdx.x;
  const int lane = tid & 63;
  const int wv = (blockIdx.x * 256 + tid) >> 6;
  const int nw = (gridDim.x * 256) >> 6;
  const float bv = b[lane];
  float s1 = 0.f, s2 = 0.f;

  for (int n = wv; n < N; n += nw){
    float acc = gather_row(rp, cs, t2, n, lane);
    size_t idx = (size_t)n * HIDDEN + lane;
    float v = (h[idx] + acc * norm_in[n] + bv) * SCALE_C;
    h[idx] = v;
    s1 += v; s2 += v * v;
  }

  __shared__ float l1[256], l2[256];
  l1[tid] = s1; l2[tid] = s2;
  __syncthreads();
  if (tid < 64){
    float a1 = l1[tid] + l1[tid+64] + l1[tid+128] + l1[tid+192];
    float a2 = l2[tid] + l2[tid+64] + l2[tid+128] + l2[tid+192];
    bnpart[blockIdx.x * 128 + tid] = a1;
    bnpart[blockIdx.x * 128 + 64 + tid] = a2;
  }
}

// ---------- BN reduce stage 1 ----------
__global__ __launch_bounds__(256) void k_bnred(const float* __restrict__ bnpart,
    float* __restrict__ bnred, int nblk){
  int col  = threadIdx.x & 127;
  int half = threadIdx.x >> 7;
  int rows = nblk / RED_BLK;
  int r0 = blockIdx.x * rows;
  float s = 0.f;
  for (int r = half; r < rows; r += 2)
    s += bnpart[(size_t)(r0 + r) * 128 + col];
  __shared__ float sh[256];
  sh[threadIdx.x] = s;
  __syncthreads();
  if (threadIdx.x < 128)
    bnred[blockIdx.x * 128 + threadIdx.x] = sh[threadIdx.x] + sh[threadIdx.x + 128];
}

// ---------- BN finalize ----------
__global__ void k_bnfin(const float* __restrict__ bnred,
    const float* __restrict__ gamma, const float* __restrict__ beta,
    float* __restrict__ bnab, float invN){
  int c = threadIdx.x;  // 64 threads
  float s1 = 0.f, s2 = 0.f;
  #pragma unroll
  for (int b = 0; b < RED_BLK; ++b){ s1 += bnred[b*128 + c]; s2 += bnred[b*128 + 64 + c]; }
  float mu  = s1 * invN;
  float var = s2 * invN - mu * mu;               // biased variance
  float rstd = rsqrtf(var + BN_EPS);
  float sc = gamma[c] * rstd;
  bnab[c] = sc;
  bnab[64 + c] = beta[c] - mu * sc;
}

// ---------- BN apply (in place on h == d_out), float4 ----------
__global__ void k_bnapply(float* __restrict__ h, const float* __restrict__ bnab, long total4){
  long i = (long)blockIdx.x * blockDim.x + threadIdx.x;
  if (i < total4){
    int c = (int)((i * 4) & 63);
    float4 v = ((float4*)h)[i];
    v.x = fmaf(v.x, bnab[c],     bnab[64 + c]);
    v.y = fmaf(v.y, bnab[c + 1], bnab[65 + c]);
    v.z = fmaf(v.z, bnab[c + 2], bnab[66 + c]);
    v.w = fmaf(v.w, bnab[c + 3], bnab[67 + c]);
    ((float4*)h)[i] = v;
  }
}

extern "C" void kernel_launch(void* const* d_in, const int* in_sizes, int n_in,
                              void* d_out, int out_size, void* d_ws, size_t ws_size,
                              hipStream_t stream){
  const int* src = (const int*)d_in[0];
  const int* dst = (const int*)d_in[1];
  const float* x     = (const float*)d_in[2];
  const float* fc_w  = (const float*)d_in[3];
  const float* fc_b  = (const float*)d_in[4];
  const float* w1    = (const float*)d_in[5];
  const float* b1    = (const float*)d_in[6];
  const float* w2    = (const float*)d_in[7];
  const float* b2    = (const float*)d_in[8];
  const float* gamma = (const float*)d_in[9];
  const float* beta  = (const float*)d_in[10];
  const int E = in_sizes[0];
  const int N = in_sizes[2] / INFEAT;
  const int NB = (N + 255) / 256;
  const int EB = (E + 255) / 256;
  const int GB = (N + 127) / 128;
  const int TOT = EB + GB;

  // h lives in d_out (fully overwritten before any read; BN apply in-place)
  float* h = (float*)d_out;

  // workspace carve (~58 MB)
  float* t1       = (float*)d_ws;                       // N*64 f32
  float* t2       = t1 + (size_t)N * HIDDEN;            // N*64 f32
  float* norm_out = t2 + (size_t)N * HIDDEN;            // N
  float* norm_in  = norm_out + N;                       // N
  float* bnpart   = norm_in + N;                        // AGG_GRID*128
  float* bnred    = bnpart + AGG_GRID * 128;            // RED_BLK*128
  float* bnab     = bnred + RED_BLK * 128;              // 128
  int*   degO     = (int*)(bnab + 128);                 // N
  int*   degI     = degO + N;                           // N
  int*   rp       = degI + N;                           // N+1
  int*   cur      = rp + N + 1;                         // N
  int*   bsum     = cur + N;                            // 512
  int*   cs       = bsum + 512;                         // E

  // ---- zero degree arrays ----
  hipMemsetAsync(degO, 0, 2 * (size_t)N * sizeof(int), stream);

  // ---- mega1: histograms || fc GEMM ----
  k_mega1<<<TOT, 256, 0, stream>>>(src, dst, degO, degI, E,
                                   x, fc_w, fc_b, h, N, GB, TOT);

  // ---- scans (rp, cur) + norms ----
  k_scan1<<<NB, 256, 0, stream>>>(degI, bsum, N);
  k_scan2<<<1, 512, 0, stream>>>(bsum, NB);
  k_scan3<<<NB, 256, 0, stream>>>(degI, degO, bsum, rp, cur, norm_out, norm_in, N, E);

  // ---- mega2: CSR placement || gemm1 (t1 = (h@w1)*norm_out) ----
  k_mega2<<<TOT, 256, 0, stream>>>(src, dst, cur, cs, E,
                                   h, w1, t1, norm_out, N, GB, TOT);

  // ---- fused conv1 aggregate + conv2 gemm: h = comb(h, gather(t1)); t2 = (h@w2)*norm_out ----
  k_aggmv<<<AGG_GRID, 256, 0, stream>>>(rp, cs, t1, norm_in, norm_out, b1, w2, h, t2, N);

  // ---- conv2 aggregate + BN partials ----
  k_agg2<<<AGG_GRID, 256, 0, stream>>>(rp, cs, t2, norm_in, b2, h, bnpart, N);

  // ---- batchnorm (two-stage parallel reduction) ----
  k_bnred<<<RED_BLK, 256, 0, stream>>>(bnpart, bnred, AGG_GRID);
  k_bnfin<<<1, 64, 0, stream>>>(bnred, gamma, beta, bnab, 1.0f / (float)N);
  long total4 = (long)N * HIDDEN / 4;
  k_bnapply<<<(int)((total4 + 255) / 256), 256, 0, stream>>>(h, bnab, total4);
}

// Round 10
// 377.540 us; speedup vs baseline: 1.0879x; 1.0879x over previous
//
#include <hip/hip_runtime.h>

#define HIDDEN 64
#define INFEAT 128
#define SCALE_C 0.70710678118654752f
#define BN_EPS 1e-5f
#define AGG_GRID 2048
#define RED_BLK 32

// ---------- lane broadcast helper (VALU readlane, uniform lane index) ----------
__device__ __forceinline__ int rli(int v, int l){ return __builtin_amdgcn_readlane(v, l); }

// ---------- device bodies ----------
// histogram + per-edge rank within dst bucket (atomicAdd return value)
__device__ __forceinline__ void hist_body(int bid, const int* __restrict__ src,
    const int* __restrict__ dst, int* __restrict__ degO, int* __restrict__ degI,
    int* __restrict__ rank, int E){
  int e = bid * 256 + threadIdx.x;
  if (e < E){
    atomicAdd(&degO[src[e]], 1);
    rank[e] = atomicAdd(&degI[dst[e]], 1);   // unique slot within dst bucket
  }
}

// atomic-free CSR placement: pos = rp[dst] + rank
__device__ __forceinline__ void place_body(int bid, const int* __restrict__ src,
    const int* __restrict__ dst, const int* __restrict__ rank,
    const int* __restrict__ rp, int* __restrict__ cs, int E){
  int e = bid * 256 + threadIdx.x;
  if (e < E){
    cs[rp[dst[e]] + rank[e]] = src[e];
  }
}

// GEMM body: Y[N][64] = X[N][KDIM] @ W[KDIM][64] (+B) (opt: row scale by nrm)
template<int KDIM, bool ADDB, bool SCALEROW>
__device__ __forceinline__ void gemm_body(int bid, const float* __restrict__ X,
    const float* __restrict__ W, const float* __restrict__ B,
    float* __restrict__ Y, const float* __restrict__ nrm, int N)
{
  __shared__ float xl[128 * 33];
  const int tid  = threadIdx.x;
  const int lane = tid & 63;
  const int wid  = __builtin_amdgcn_readfirstlane(tid >> 6);  // wave-uniform
  const int nodehalf = wid >> 1;               // 0/1
  const int c0 = (wid & 1) * 32;               // column offset (uniform)
  const int base = bid * 128;
  const int myNode = nodehalf * 64 + lane;     // 0..127
  const int gnode = base + myNode;

  float acc[32];
  #pragma unroll
  for (int c = 0; c < 32; ++c) acc[c] = ADDB ? B[c0 + c] : 0.f;

  constexpr int NCHUNK = KDIM / 32;
  #pragma unroll 1
  for (int ck = 0; ck < NCHUNK; ++ck){
    __syncthreads();
    #pragma unroll
    for (int i = 0; i < 4; ++i){
      int f  = i * 256 + tid;        // float4 id, 0..1023
      int nd = f >> 3;               // 0..127
      int kq = f & 7;                // 0..7
      float4 v = make_float4(0.f, 0.f, 0.f, 0.f);
      if (base + nd < N)
        v = *(const float4*)(X + (size_t)(base + nd) * KDIM + ck * 32 + kq * 4);
      float* p = &xl[nd * 33 + kq * 4];
      p[0] = v.x; p[1] = v.y; p[2] = v.z; p[3] = v.w;
    }
    __syncthreads();
    const float* wrow = W + (size_t)ck * 32 * HIDDEN + c0;   // uniform base
    #pragma unroll
    for (int k = 0; k < 32; ++k){
      float xv = xl[myNode * 33 + k];
      #pragma unroll
      for (int c = 0; c < 32; ++c)
        acc[c] = fmaf(xv, wrow[k * HIDDEN + c], acc[c]);     // W via s_load
    }
  }

  if (gnode < N){
    float sc = SCALEROW ? nrm[gnode] : 1.f;
    float4* yp = (float4*)(Y + (size_t)gnode * HIDDEN + c0);
    #pragma unroll
    for (int j = 0; j < 8; ++j)
      yp[j] = make_float4(acc[4*j]*sc, acc[4*j+1]*sc, acc[4*j+2]*sc, acc[4*j+3]*sc);
  }
}

// Bresenham role spread
__device__ __forceinline__ int role_gemm_idx(int b, int GB, int TOT, int& histIdx){
  int fb  = (int)(((long)b * GB) / TOT);
  int fb1 = (int)(((long)(b + 1) * GB) / TOT);
  histIdx = b - fb;
  return (fb1 > fb) ? fb : -1;
}

// ---------- mega1: degree histograms + ranks || fc GEMM ----------
__global__ __launch_bounds__(256) void k_mega1(const int* __restrict__ src,
    const int* __restrict__ dst, int* __restrict__ degO, int* __restrict__ degI,
    int* __restrict__ rank, int E,
    const float* __restrict__ x, const float* __restrict__ fc_w,
    const float* __restrict__ fc_b, float* __restrict__ h, int N, int GB, int TOT){
  int hIdx;
  int g = role_gemm_idx(blockIdx.x, GB, TOT, hIdx);
  if (g >= 0) gemm_body<INFEAT, true, false>(g, x, fc_w, fc_b, h, nullptr, N);
  else        hist_body(hIdx, src, dst, degO, degI, rank, E);
}

// ---------- mega2: atomic-free CSR placement || gemm1 (t = (h@w1)*norm_out) ----------
__global__ __launch_bounds__(256) void k_mega2(const int* __restrict__ src,
    const int* __restrict__ dst, const int* __restrict__ rank,
    const int* __restrict__ rp, int* __restrict__ cs, int E,
    const float* __restrict__ h, const float* __restrict__ w1,
    float* __restrict__ t, const float* __restrict__ norm_out, int N, int GB, int TOT){
  int hIdx;
  int g = role_gemm_idx(blockIdx.x, GB, TOT, hIdx);
  if (g >= 0) gemm_body<HIDDEN, false, true>(g, h, w1, nullptr, t, norm_out, N);
  else        place_body(hIdx, src, dst, rank, rp, cs, E);
}

// ---------- standalone gemm2 ----------
__global__ __launch_bounds__(256) void k_gemm64(const float* __restrict__ X,
    const float* __restrict__ W, float* __restrict__ Y,
    const float* __restrict__ nrm, int N){
  gemm_body<HIDDEN, false, true>(blockIdx.x, X, W, nullptr, Y, nrm, N);
}

// ---------- scan step 1 ----------
__global__ void k_scan1(const int* __restrict__ deg, int* __restrict__ bsum, int N){
  __shared__ int sh[256];
  int t = threadIdx.x;
  int i = blockIdx.x * 256 + t;
  sh[t] = (i < N) ? deg[i] : 0;
  __syncthreads();
  for (int ofs = 128; ofs > 0; ofs >>= 1){
    if (t < ofs) sh[t] += sh[t + ofs];
    __syncthreads();
  }
  if (t == 0) bsum[blockIdx.x] = sh[0];
}

// ---------- scan step 2 ----------
__global__ void k_scan2(int* __restrict__ bsum, int NB){
  __shared__ int sh[512];
  int t = threadIdx.x;
  int v = (t < NB) ? bsum[t] : 0;
  sh[t] = v;
  __syncthreads();
  for (int ofs = 1; ofs < 512; ofs <<= 1){
    int u = (t >= ofs) ? sh[t - ofs] : 0;
    __syncthreads();
    sh[t] += u;
    __syncthreads();
  }
  if (t < NB) bsum[t] = sh[t] - v;   // exclusive
}

// ---------- scan step 3: rp + norms ----------
__global__ void k_scan3(const int* __restrict__ degI, const int* __restrict__ degO,
                        const int* __restrict__ bofs, int* __restrict__ rp,
                        float* __restrict__ norm_out, float* __restrict__ norm_in,
                        int N, int E){
  __shared__ int sh[256];
  int t = threadIdx.x;
  int i = blockIdx.x * 256 + t;
  int v = (i < N) ? degI[i] : 0;
  sh[t] = v;
  __syncthreads();
  for (int ofs = 1; ofs < 256; ofs <<= 1){
    int u = (t >= ofs) ? sh[t - ofs] : 0;
    __syncthreads();
    sh[t] += u;
    __syncthreads();
  }
  if (i < N){
    int excl = sh[t] - v + bofs[blockIdx.x];
    rp[i] = excl;
    if (i == N - 1) rp[N] = E;
    norm_out[i] = rsqrtf((float)max(degO[i], 1));
    norm_in[i]  = rsqrtf((float)max(v, 1));
  }
}

// ---------- gather accumulate (8-deep pipeline, readlane broadcast) ----------
__device__ __forceinline__ float gather_row(const int* __restrict__ rp,
    const int* __restrict__ cs, const float* __restrict__ t, int n, int lane){
  const int start = rp[n], end = rp[n + 1];
  float acc = 0.f;
  for (int j0 = start; j0 < end; j0 += 64){
    int cnt = end - j0; if (cnt > 64) cnt = 64;
    int sidx = (j0 + lane < end) ? cs[j0 + lane] : 0;
    int d = 0;
    for (; d + 8 <= cnt; d += 8){
      int a0 = rli(sidx, d),   a1 = rli(sidx, d+1);
      int a2 = rli(sidx, d+2), a3 = rli(sidx, d+3);
      int a4 = rli(sidx, d+4), a5 = rli(sidx, d+5);
      int a6 = rli(sidx, d+6), a7 = rli(sidx, d+7);
      float v0 = t[(size_t)a0 * HIDDEN + lane];
      float v1 = t[(size_t)a1 * HIDDEN + lane];
      float v2 = t[(size_t)a2 * HIDDEN + lane];
      float v3 = t[(size_t)a3 * HIDDEN + lane];
      float v4 = t[(size_t)a4 * HIDDEN + lane];
      float v5 = t[(size_t)a5 * HIDDEN + lane];
      float v6 = t[(size_t)a6 * HIDDEN + lane];
      float v7 = t[(size_t)a7 * HIDDEN + lane];
      acc += v0; acc += v1; acc += v2; acc += v3;
      acc += v4; acc += v5; acc += v6; acc += v7;
    }
    for (; d < cnt; ++d)
      acc += t[(size_t)rli(sidx, d) * HIDDEN + lane];
  }
  return acc;
}

// ---------- fused CSR aggregate + residual combine (+ BN partials) ----------
template<bool BN>
__global__ __launch_bounds__(256) void k_agg(const int* __restrict__ rp, const int* __restrict__ cs,
    const float* __restrict__ t, const float* __restrict__ norm_in,
    const float* __restrict__ b, float* __restrict__ h, float* __restrict__ bnpart, int N)
{
  const int tid = threadIdx.x;
  const int lane = tid & 63;
  const int wv = (blockIdx.x * 256 + tid) >> 6;
  const int nw = (gridDim.x * 256) >> 6;
  const float bv = b[lane];
  float s1 = 0.f, s2 = 0.f;

  for (int n = wv; n < N; n += nw){
    float acc = gather_row(rp, cs, t, n, lane);
    size_t idx = (size_t)n * HIDDEN + lane;
    float v = (h[idx] + acc * norm_in[n] + bv) * SCALE_C;
    h[idx] = v;
    if (BN){ s1 += v; s2 += v * v; }
  }

  if (BN){
    __shared__ float l1[256], l2[256];
    l1[tid] = s1; l2[tid] = s2;
    __syncthreads();
    if (tid < 64){
      float a1 = l1[tid] + l1[tid+64] + l1[tid+128] + l1[tid+192];
      float a2 = l2[tid] + l2[tid+64] + l2[tid+128] + l2[tid+192];
      bnpart[blockIdx.x * 128 + tid] = a1;
      bnpart[blockIdx.x * 128 + 64 + tid] = a2;
    }
  }
}

// ---------- BN reduce stage 1 ----------
__global__ __launch_bounds__(256) void k_bnred(const float* __restrict__ bnpart,
    float* __restrict__ bnred, int nblk){
  int col  = threadIdx.x & 127;
  int half = threadIdx.x >> 7;
  int rows = nblk / RED_BLK;
  int r0 = blockIdx.x * rows;
  float s = 0.f;
  for (int r = half; r < rows; r += 2)
    s += bnpart[(size_t)(r0 + r) * 128 + col];
  __shared__ float sh[256];
  sh[threadIdx.x] = s;
  __syncthreads();
  if (threadIdx.x < 128)
    bnred[blockIdx.x * 128 + threadIdx.x] = sh[threadIdx.x] + sh[threadIdx.x + 128];
}

// ---------- BN finalize ----------
__global__ void k_bnfin(const float* __restrict__ bnred,
    const float* __restrict__ gamma, const float* __restrict__ beta,
    float* __restrict__ bnab, float invN){
  int c = threadIdx.x;  // 64 threads
  float s1 = 0.f, s2 = 0.f;
  #pragma unroll
  for (int b = 0; b < RED_BLK; ++b){ s1 += bnred[b*128 + c]; s2 += bnred[b*128 + 64 + c]; }
  float mu  = s1 * invN;
  float var = s2 * invN - mu * mu;               // biased variance
  float rstd = rsqrtf(var + BN_EPS);
  float sc = gamma[c] * rstd;
  bnab[c] = sc;
  bnab[64 + c] = beta[c] - mu * sc;
}

// ---------- BN apply (in place on h == d_out), float4 ----------
__global__ void k_bnapply(float* __restrict__ h, const float* __restrict__ bnab, long total4){
  long i = (long)blockIdx.x * blockDim.x + threadIdx.x;
  if (i < total4){
    int c = (int)((i * 4) & 63);
    float4 v = ((float4*)h)[i];
    v.x = fmaf(v.x, bnab[c],     bnab[64 + c]);
    v.y = fmaf(v.y, bnab[c + 1], bnab[65 + c]);
    v.z = fmaf(v.z, bnab[c + 2], bnab[66 + c]);
    v.w = fmaf(v.w, bnab[c + 3], bnab[67 + c]);
    ((float4*)h)[i] = v;
  }
}

extern "C" void kernel_launch(void* const* d_in, const int* in_sizes, int n_in,
                              void* d_out, int out_size, void* d_ws, size_t ws_size,
                              hipStream_t stream){
  const int* src = (const int*)d_in[0];
  const int* dst = (const int*)d_in[1];
  const float* x     = (const float*)d_in[2];
  const float* fc_w  = (const float*)d_in[3];
  const float* fc_b  = (const float*)d_in[4];
  const float* w1    = (const float*)d_in[5];
  const float* b1    = (const float*)d_in[6];
  const float* w2    = (const float*)d_in[7];
  const float* b2    = (const float*)d_in[8];
  const float* gamma = (const float*)d_in[9];
  const float* beta  = (const float*)d_in[10];
  const int E = in_sizes[0];
  const int N = in_sizes[2] / INFEAT;
  const int NB = (N + 255) / 256;
  const int EB = (E + 255) / 256;
  const int GB = (N + 127) / 128;
  const int TOT = EB + GB;

  // h lives in d_out (fully overwritten before any read; BN apply in-place)
  float* h = (float*)d_out;

  // workspace carve (~37 MB)
  float* t        = (float*)d_ws;                       // N*64 f32
  float* norm_out = t + (size_t)N * HIDDEN;             // N
  float* norm_in  = norm_out + N;                       // N
  float* bnpart   = norm_in + N;                        // AGG_GRID*128
  float* bnred    = bnpart + AGG_GRID * 128;            // RED_BLK*128
  float* bnab     = bnred + RED_BLK * 128;              // 128
  int*   degO     = (int*)(bnab + 128);                 // N
  int*   degI     = degO + N;                           // N
  int*   rp       = degI + N;                           // N+1
  int*   bsum     = rp + N + 1;                         // 512
  int*   rank     = bsum + 512;                         // E
  int*   cs       = rank + E;                           // E

  // ---- zero degree arrays ----
  hipMemsetAsync(degO, 0, 2 * (size_t)N * sizeof(int), stream);

  // ---- mega1: histograms + ranks || fc GEMM ----
  k_mega1<<<TOT, 256, 0, stream>>>(src, dst, degO, degI, rank, E,
                                   x, fc_w, fc_b, h, N, GB, TOT);

  // ---- scans (rp) + norms ----
  k_scan1<<<NB, 256, 0, stream>>>(degI, bsum, N);
  k_scan2<<<1, 512, 0, stream>>>(bsum, NB);
  k_scan3<<<NB, 256, 0, stream>>>(degI, degO, bsum, rp, norm_out, norm_in, N, E);

  // ---- mega2: atomic-free placement || gemm1 (t = (h@w1)*norm_out) ----
  k_mega2<<<TOT, 256, 0, stream>>>(src, dst, rank, rp, cs, E,
                                   h, w1, t, norm_out, N, GB, TOT);

  // ---- conv1 aggregate: h = (h + gather(t)*norm_in + b1)*sqrt(1/2) ----
  k_agg<false><<<AGG_GRID, 256, 0, stream>>>(rp, cs, t, norm_in, b1, h, nullptr, N);

  // ---- conv2 ----
  k_gemm64<<<GB, 256, 0, stream>>>(h, w2, t, norm_out, N);
  k_agg<true><<<AGG_GRID, 256, 0, stream>>>(rp, cs, t, norm_in, b2, h, bnpart, N);

  // ---- batchnorm (two-stage parallel reduction) ----
  k_bnred<<<RED_BLK, 256, 0, stream>>>(bnpart, bnred, AGG_GRID);
  k_bnfin<<<1, 64, 0, stream>>>(bnred, gamma, beta, bnab, 1.0f / (float)N);
  long total4 = (long)N * HIDDEN / 4;
  k_bnapply<<<(int)((total4 + 255) / 256), 256, 0, stream>>>(h, bnab, total4);
}